// Round 5
// baseline (5321.346 us; speedup 1.0000x reference)
//
#include <hip/hip_runtime.h>
#include <hip/hip_bf16.h>
#include <cstdio>
#include <cstdint>

#define BATCH 8
#define CIN 256
#define L0 16384
#define NRES 32
#define NSKIP 512
#define NL 50
#define FINAL_LEN 11269
#define NTROW 11392  // 89 * 128 column-tile rows
#define NBLK 512     // persistent-kernel grid (2 blocks/CU x 256 CUs)

typedef __attribute__((ext_vector_type(4))) float f32x4v;
typedef __attribute__((ext_vector_type(8))) short s16x8;
typedef __attribute__((ext_vector_type(4))) short s16x4;

// 16B-chunk swizzle within 64B rows: involution, gives 2-way-max bank aliasing
__device__ __forceinline__ int SWS(int r, int s) {
    return s ^ (r & 3) ^ ((r >> 2) & 1);
}
__device__ __forceinline__ short f2bf(float f) {
    __hip_bfloat16 h = __float2bfloat16(f);
    return *reinterpret_cast<short*>(&h);
}
__device__ __forceinline__ void gload16(const void* g, void* l) {
    __builtin_amdgcn_global_load_lds(
        (const __attribute__((address_space(1))) unsigned int*)g,
        (__attribute__((address_space(3))) unsigned int*)l, 16, 0, 0);
}

// ---------------------------------------------------------------- global barrier
__global__ void k_init_bar(int* c) { if (threadIdx.x < 64) c[threadIdx.x] = 0; }

__device__ __forceinline__ void gbarrier(int* cnt, int target) {
    __syncthreads();
    if (threadIdx.x == 0) {
        __threadfence();  // release: make this block's writes device-visible
        __hip_atomic_fetch_add(cnt, 1, __ATOMIC_RELEASE, __HIP_MEMORY_SCOPE_AGENT);
        int it = 0;
        while (__hip_atomic_load(cnt, __ATOMIC_ACQUIRE, __HIP_MEMORY_SCOPE_AGENT) < target) {
            __builtin_amdgcn_s_sleep(2);
            if (++it > (1 << 20)) break;  // bailout: never hang the harness
        }
        __threadfence();  // acquire: invalidate stale cache lines
    }
    __syncthreads();
}

// ---------------------------------------------------------------- bias sum
__global__ void k_bias_sum(const float* __restrict__ b_skip, float* __restrict__ bsum) {
    int o = threadIdx.x;
    if (o < NSKIP) {
        float s = 0.f;
        for (int i = 0; i < NL; ++i) s += b_skip[i * NSKIP + o];
        bsum[o] = s;
    }
}

// ---------------------------------------------------------------- weight converts (fp32 -> bf16, pre-swizzled)
__global__ __launch_bounds__(256) void k_cvt_skip(const float* __restrict__ w, short* __restrict__ out) {
    int idx = blockIdx.x * 256 + threadIdx.x;
    if (idx >= NSKIP * NL) return;
    int o = idx % NSKIP, ly = idx / NSKIP;
    const float* src = w + ((size_t)ly * NSKIP + o) * NRES;
    size_t base = (size_t)o * (NL * NRES) + ly * NRES;
#pragma unroll
    for (int s = 0; s < 4; ++s) {
        s16x8 v;
#pragma unroll
        for (int j = 0; j < 8; ++j) v[j] = f2bf(src[s * 8 + j]);
        *reinterpret_cast<s16x8*>(out + base + SWS(o & 7, s) * 8) = v;
    }
}

__global__ __launch_bounds__(256) void k_cvt_mat(const float* __restrict__ w, short* __restrict__ out, int M) {
    int idx = blockIdx.x * 256 + threadIdx.x;
    if (idx >= M * 16) return;
    int m = idx >> 4, kc = idx & 15;
    const float* src = w + (size_t)m * 512 + kc * 32;
    size_t base = (size_t)m * 512 + kc * 32;
#pragma unroll
    for (int s = 0; s < 4; ++s) {
        s16x8 v;
#pragma unroll
        for (int j = 0; j < 8; ++j) v[j] = f2bf(src[s * 8 + j]);
        *reinterpret_cast<s16x8*>(out + base + SWS(m & 7, s) * 8) = v;
    }
}

// combined gated-conv weights: Wc[i][64 out][64 k], k = tap*32 + c ; Wres[i][32][32]
__global__ __launch_bounds__(256) void k_cvt_w(
    const float* __restrict__ ws, const float* __restrict__ wt, const float* __restrict__ wr,
    short* __restrict__ Wc, short* __restrict__ Wres) {
    int idx = blockIdx.x * 256 + threadIdx.x;
    if (idx < NL * 64 * 64) {
        int k = idx & 63, o = (idx >> 6) & 63, i = idx >> 12;
        int c = k & 31, tap = k >> 5;
        float v = (o < 32) ? ws[((i * NRES + o) * NRES + c) * 2 + tap]
                           : wt[((i * NRES + (o - 32)) * NRES + c) * 2 + tap];
        Wc[idx] = f2bf(v);
    } else {
        int j = idx - NL * 64 * 64;
        if (j < NL * 32 * 32) Wres[j] = f2bf(wr[j]);
    }
}

// ---------------------------------------------------------------- zero gatesT tail rows
__global__ __launch_bounds__(256) void k_zero_tail(short* __restrict__ gT) {
    int i = blockIdx.x * 256 + threadIdx.x;
    const int per_b = (NTROW - FINAL_LEN) * 200;
    if (i >= BATCH * per_b) return;
    int b = i / per_b, r = i % per_b;
    int row = FINAL_LEN + r / 200, c = r % 200;
    s16x8 z = {0, 0, 0, 0, 0, 0, 0, 0};
    *reinterpret_cast<s16x8*>(gT + ((size_t)b * NTROW + row) * (NL * NRES) + c * 8) = z;
}

// ---------------------------------------------------------------- input 1x1 conv 256->32, t-major fp32 out
__global__ __launch_bounds__(256) void k_conv_in(
    const float* __restrict__ x, const float* __restrict__ w,
    const float* __restrict__ bias, float* __restrict__ outT) {
    const int b = blockIdx.y;
    const int t = blockIdx.x * 256 + threadIdx.x;
    float acc[NRES];
#pragma unroll
    for (int o = 0; o < NRES; ++o) acc[o] = bias[o];
    const float* xp = x + (size_t)b * CIN * L0 + t;
    for (int c = 0; c < CIN; ++c) {
        float xv = xp[(size_t)c * L0];
#pragma unroll
        for (int o = 0; o < NRES; ++o) acc[o] = fmaf(w[o * CIN + c], xv, acc[o]);
    }
    float* op = outT + ((size_t)b * L0 + t) * NRES;
#pragma unroll
    for (int s = 0; s < 8; ++s) {
        f32x4v v = {acc[s * 4], acc[s * 4 + 1], acc[s * 4 + 2], acc[s * 4 + 3]};
        *reinterpret_cast<f32x4v*>(op + s * 4) = v;
    }
}

// ---------------------------------------------------------------- persistent all-layer kernel
// residual stream fp32 t-major [b][t][32]; gates staged to gatesT (bf16, swizzled)
__global__ __launch_bounds__(256, 2) void k_layers_all(
    float* __restrict__ bufA, float* __restrict__ bufB,
    short* __restrict__ gatesT,
    const short* __restrict__ WcAll, const short* __restrict__ WrAll,
    const float* __restrict__ bsigAll, const float* __restrict__ btanAll,
    const float* __restrict__ bresAll, int* __restrict__ barcnt) {
    const int tid = threadIdx.x;
    const int l = tid & 63, wv = tid >> 6;
    const int lr = l & 15, lg = l >> 4;
    const int bid = blockIdx.x;
    const int tx = bid >> 3, b = bid & 7;

    __shared__ short gsm[4][64][40];  // per-wave gate slices (pad 40: <=2-way banks)

    float* sF = bufA;
    float* dF = bufB;
    int len = L0;

    for (int i = 0; i < NL; ++i) {
        const int d = 1 << (i % 10);
        const int out_len = len - d;
        const int tiles = (out_len + 255) >> 8;

        if (tx < tiles) {
            const short* Wc = WcAll + (size_t)i * 4096;
            const short* Wr = WrAll + (size_t)i * 1024;
            s16x8 aW[4][2], aR[2];
#pragma unroll
            for (int mf = 0; mf < 4; ++mf)
#pragma unroll
                for (int kf = 0; kf < 2; ++kf)
                    aW[mf][kf] = *reinterpret_cast<const s16x8*>(&Wc[(mf * 16 + lr) * 64 + kf * 32 + lg * 8]);
#pragma unroll
            for (int mf = 0; mf < 2; ++mf)
                aR[mf] = *reinterpret_cast<const s16x8*>(&Wr[(mf * 16 + lr) * 32 + lg * 8]);

            float bs2[2][4], bt2[2][4], br2[2][4];
#pragma unroll
            for (int mf = 0; mf < 2; ++mf)
#pragma unroll
                for (int j = 0; j < 4; ++j) {
                    int o = mf * 16 + lg * 4 + j;
                    bs2[mf][j] = bsigAll[i * 32 + o];
                    bt2[mf][j] = btanAll[i * 32 + o];
                    br2[mf][j] = bresAll[i * 32 + o];
                }

            const float* sFb = sF + (size_t)b * L0 * NRES;
            float* dFb = dF + (size_t)b * L0 * NRES;
            short* go = gatesT + (size_t)i * NRES + (size_t)b * NTROW * (NL * NRES);
            const int t0w = tx * 256 + wv * 64;
            const int t0g = out_len - FINAL_LEN;

#pragma unroll 1
            for (int nf = 0; nf < 4; ++nf) {
                const int tl = nf * 16 + lr;
                const int t = t0w + tl;
                const int tc = t < out_len ? t : (out_len - 1);
                // B-fragments: fp32 t-major rows -> bf16 in-register (identical to old shadow values)
                f32x4v x0a = *reinterpret_cast<const f32x4v*>(&sFb[(size_t)tc * NRES + lg * 8]);
                f32x4v x0b = *reinterpret_cast<const f32x4v*>(&sFb[(size_t)tc * NRES + lg * 8 + 4]);
                f32x4v x1a = *reinterpret_cast<const f32x4v*>(&sFb[(size_t)(tc + d) * NRES + lg * 8]);
                f32x4v x1b = *reinterpret_cast<const f32x4v*>(&sFb[(size_t)(tc + d) * NRES + lg * 8 + 4]);
                s16x8 bx0, bx1;
#pragma unroll
                for (int j = 0; j < 4; ++j) {
                    bx0[j] = f2bf(x0a[j]); bx0[4 + j] = f2bf(x0b[j]);
                    bx1[j] = f2bf(x1a[j]); bx1[4 + j] = f2bf(x1b[j]);
                }

                f32x4v acc[4];
#pragma unroll
                for (int mf = 0; mf < 4; ++mf) acc[mf] = {0.f, 0.f, 0.f, 0.f};
#pragma unroll
                for (int mf = 0; mf < 4; ++mf) {
                    acc[mf] = __builtin_amdgcn_mfma_f32_16x16x32_bf16(aW[mf][0], bx0, acc[mf], 0, 0, 0);
                    acc[mf] = __builtin_amdgcn_mfma_f32_16x16x32_bf16(aW[mf][1], bx1, acc[mf], 0, 0, 0);
                }

                // gate nonlinearity: sig frag mf, tanh frag mf+2 — same lane, same slot
#pragma unroll
                for (int mf = 0; mf < 2; ++mf) {
                    s16x4 gq;
#pragma unroll
                    for (int j = 0; j < 4; ++j) {
                        float Ps = acc[mf][j] + bs2[mf][j];
                        float Pt = acc[mf + 2][j] + bt2[mf][j];
                        float sg = 1.f / (1.f + __expf(-Ps));
                        float e2 = __expf(2.f * Pt);
                        float th = 1.f - 2.f / (e2 + 1.f);
                        gq[j] = f2bf(sg * th);
                    }
                    *reinterpret_cast<s16x4*>(&gsm[wv][tl][mf * 16 + lg * 4]) = gq;
                }
                // per-wave LDS producer->consumer: wait writes complete (no block barrier needed)
                asm volatile("s_waitcnt lgkmcnt(0)" ::: "memory");

                s16x8 bg = *reinterpret_cast<const s16x8*>(&gsm[wv][tl][lg * 8]);
                f32x4v accR[2];
#pragma unroll
                for (int mf = 0; mf < 2; ++mf) {
                    accR[mf] = {0.f, 0.f, 0.f, 0.f};
                    accR[mf] = __builtin_amdgcn_mfma_f32_16x16x32_bf16(aR[mf], bg, accR[mf], 0, 0, 0);
                }

                if (t < out_len) {
#pragma unroll
                    for (int mf = 0; mf < 2; ++mf) {
                        f32x4v rv = *reinterpret_cast<const f32x4v*>(&sFb[(size_t)(t + d) * NRES + mf * 16 + lg * 4]);
                        f32x4v ov;
#pragma unroll
                        for (int j = 0; j < 4; ++j) ov[j] = accR[mf][j] + br2[mf][j] + rv[j];
                        *reinterpret_cast<f32x4v*>(&dFb[(size_t)t * NRES + mf * 16 + lg * 4]) = ov;
                    }
                }
            }
            asm volatile("s_waitcnt lgkmcnt(0)" ::: "memory");

            // coalesced gate repack: full 64B-line stores (SWS permutes 16B chunks in-line)
#pragma unroll
            for (int k = 0; k < 4; ++k) {
                int r = k * 16 + (l >> 2);
                int t = t0w + r;
                int c = l & 3;
                if (t >= t0g && t < out_len) {
                    int tg = t - t0g;
                    s16x8 gv = *reinterpret_cast<const s16x8*>(&gsm[wv][r][c * 8]);
                    *reinterpret_cast<s16x8*>(&go[(size_t)tg * (NL * NRES) + SWS(tg & 7, c) * 8]) = gv;
                }
            }
        }

        if (i + 1 < NL) gbarrier(barcnt, NBLK * (i + 1));
        float* tf = sF; sF = dF; dF = tf;
        len = out_len;
    }
}

// ---------------------------------------------------------------- MFMA GEMM (XCD-locality 1D grid decode)
// blocks with same t-panel land on same XCD (ids congruent mod 8) -> B panel L2 reuse across m-tiles
template <int KTOT, bool DOELU, int OUTMODE, int NM>
__global__ __launch_bounds__(256) void k_mm(
    const short* __restrict__ A, const float* __restrict__ bias,
    const short* __restrict__ B, short* __restrict__ outS,
    float* __restrict__ outF, int Mtot) {
    const int tid = threadIdx.x;
    const int l = tid & 63, w = tid >> 6;

    const int id = blockIdx.x;
    const int rr = id % (8 * NM);
    const int ttile = (id / (8 * NM)) * 8 + (rr & 7);
    if (ttile >= NTROW / 128) return;
    const int t0 = ttile * 128;
    const int m0 = (rr >> 3) * 128;
    const int bb = blockIdx.z;

    __shared__ __attribute__((aligned(16))) char Asm_[2][8192];
    __shared__ __attribute__((aligned(16))) char Bsm_[2][8192];

    const char* Ag = (const char*)A;
    const char* Bg = (const char*)B + (size_t)bb * NTROW * (KTOT * 2);

    const int rstage = w * 16 + (l >> 2);
    const char* a0 = Ag + (size_t)(m0 + rstage) * (KTOT * 2) + (l & 3) * 16;
    const char* a1 = a0 + (size_t)64 * (KTOT * 2);
    const char* b0 = Bg + (size_t)(t0 + rstage) * (KTOT * 2) + (l & 3) * 16;
    const char* b1 = b0 + (size_t)64 * (KTOT * 2);

    const int wm = (w >> 1) * 64, wn = (w & 1) * 64;
    const int slotSw = ((l >> 4) ^ (l & 3) ^ ((l >> 2) & 1)) * 16;
    const int aoff = (wm + (l & 15)) * 64 + slotSw;
    const int boff = (wn + (l & 15)) * 64 + slotSw;

    f32x4v acc[4][4];
#pragma unroll
    for (int i = 0; i < 4; ++i)
#pragma unroll
        for (int j = 0; j < 4; ++j) acc[i][j] = {0.f, 0.f, 0.f, 0.f};

    constexpr int NKT = KTOT / 32;
    gload16(a0, &Asm_[0][w * 1024]);
    gload16(a1, &Asm_[0][4096 + w * 1024]);
    gload16(b0, &Bsm_[0][w * 1024]);
    gload16(b1, &Bsm_[0][4096 + w * 1024]);
    __syncthreads();

    for (int kt = 0; kt < NKT; ++kt) {
        const int cur = kt & 1;
        if (kt + 1 < NKT) {
            size_t ko = (size_t)(kt + 1) * 64;
            gload16(a0 + ko, &Asm_[cur ^ 1][w * 1024]);
            gload16(a1 + ko, &Asm_[cur ^ 1][4096 + w * 1024]);
            gload16(b0 + ko, &Bsm_[cur ^ 1][w * 1024]);
            gload16(b1 + ko, &Bsm_[cur ^ 1][4096 + w * 1024]);
        }
        s16x8 af[4], bf_[4];
#pragma unroll
        for (int i = 0; i < 4; ++i)
            af[i] = *reinterpret_cast<const s16x8*>(&Asm_[cur][aoff + i * 1024]);
#pragma unroll
        for (int i = 0; i < 4; ++i)
            bf_[i] = *reinterpret_cast<const s16x8*>(&Bsm_[cur][boff + i * 1024]);
#pragma unroll
        for (int i = 0; i < 4; ++i)
#pragma unroll
            for (int j = 0; j < 4; ++j)
                acc[i][j] = __builtin_amdgcn_mfma_f32_16x16x32_bf16(af[i], bf_[j], acc[i][j], 0, 0, 0);
        __syncthreads();
    }

    const int colc = l & 15;
    const int rowc = (l >> 4) * 4;
#pragma unroll
    for (int mf = 0; mf < 4; ++mf) {
        const int ch = m0 + wm + mf * 16 + rowc;
        const float4 bv = *reinterpret_cast<const float4*>(&bias[ch]);
        const float* bvp = (const float*)&bv;
#pragma unroll
        for (int nf = 0; nf < 4; ++nf) {
            const int t = t0 + wn + nf * 16 + colc;
            float vb[4];
#pragma unroll
            for (int j = 0; j < 4; ++j) {
                float v = acc[mf][nf][j] + bvp[j];
                if (DOELU) v = v > 0.f ? v : (__expf(v) - 1.f);
                vb[j] = v;
            }
            if (OUTMODE == 0) {
                s16x4 pv;
#pragma unroll
                for (int j = 0; j < 4; ++j) pv[j] = f2bf(vb[j]);
                size_t el = ((size_t)bb * NTROW + t) * 512 + (ch >> 5) * 32
                          + SWS(t & 7, (ch >> 3) & 3) * 8 + (ch & 7);
                *reinterpret_cast<s16x4*>(outS + el) = pv;
            } else {
                if (t < FINAL_LEN) {
#pragma unroll
                    for (int j = 0; j < 4; ++j)
                        outF[((size_t)bb * Mtot + ch + j) * FINAL_LEN + t] = vb[j];
                }
            }
        }
    }
}

// ---------------------------------------------------------------- host
extern "C" void kernel_launch(void* const* d_in, const int* in_sizes, int n_in,
                              void* d_out, int out_size, void* d_ws, size_t ws_size,
                              hipStream_t stream) {
    const float* x      = (const float*)d_in[0];
    const float* w_in   = (const float*)d_in[1];
    const float* b_in   = (const float*)d_in[2];
    const float* w_sig  = (const float*)d_in[3];
    const float* b_sig  = (const float*)d_in[4];
    const float* w_tanh = (const float*)d_in[5];
    const float* b_tanh = (const float*)d_in[6];
    const float* w_skip = (const float*)d_in[7];
    const float* b_skip = (const float*)d_in[8];
    const float* w_res  = (const float*)d_in[9];
    const float* b_res  = (const float*)d_in[10];
    const float* w_p1   = (const float*)d_in[11];
    const float* b_p1   = (const float*)d_in[12];
    const float* w_p2   = (const float*)d_in[13];
    const float* b_p2   = (const float*)d_in[14];
    float* out = (float*)d_out;

    float* bufA   = (float*)d_ws;
    float* bufB   = bufA + (size_t)BATCH * NRES * L0;
    float* bsum   = bufB + (size_t)BATCH * NRES * L0;
    short* Askip  = (short*)(bsum + NSKIP);
    short* Ap1    = Askip + (size_t)NSKIP * NL * NRES;
    short* Ap2    = Ap1 + (size_t)NSKIP * NSKIP;
    short* WcH    = Ap2 + (size_t)CIN * NSKIP;
    short* WresH  = WcH + (size_t)NL * 64 * 64;
    short* gatesT = WresH + (size_t)NL * 32 * 32;
    short* hbufT  = gatesT + (size_t)BATCH * NTROW * (NL * NRES);
    short* h2bufT = gatesT;  // alias: gatesT dead after skip GEMM
    int*   barcnt = (int*)(hbufT + (size_t)BATCH * NTROW * NSKIP);

    size_t need = (size_t)((char*)(barcnt + 64) - (char*)d_ws);
    if (ws_size < need)
        fprintf(stderr, "WS TOO SMALL: have %zu need %zu\n", ws_size, need);

    k_bias_sum<<<1, 512, 0, stream>>>(b_skip, bsum);
    k_cvt_skip<<<(NSKIP * NL + 255) / 256, 256, 0, stream>>>(w_skip, Askip);
    k_cvt_mat<<<(NSKIP * 16 + 255) / 256, 256, 0, stream>>>(w_p1, Ap1, NSKIP);
    k_cvt_mat<<<(CIN * 16 + 255) / 256, 256, 0, stream>>>(w_p2, Ap2, CIN);
    k_cvt_w<<<(NL * 64 * 64 + NL * 32 * 32 + 255) / 256, 256, 0, stream>>>(
        w_sig, w_tanh, w_res, WcH, WresH);
    k_zero_tail<<<(BATCH * (NTROW - FINAL_LEN) * 200 + 255) / 256, 256, 0, stream>>>(gatesT);
    k_init_bar<<<1, 64, 0, stream>>>(barcnt);
    k_conv_in<<<dim3(L0 / 256, BATCH), 256, 0, stream>>>(x, w_in, b_in, bufA);

    k_layers_all<<<NBLK, 256, 0, stream>>>(
        bufA, bufB, gatesT, WcH, WresH, b_sig, b_tanh, b_res, barcnt);

    k_mm<1600, true, 0, 4><<<dim3(384, 1, BATCH), 256, 0, stream>>>(Askip, bsum, gatesT, hbufT, nullptr, NSKIP);
    k_mm<512,  true, 0, 4><<<dim3(384, 1, BATCH), 256, 0, stream>>>(Ap1, b_p1, hbufT, h2bufT, nullptr, NSKIP);
    k_mm<512, false, 1, 2><<<dim3(192, 1, BATCH), 256, 0, stream>>>(Ap2, b_p2, h2bufT, nullptr, out, CIN);
}

// Round 6
// 1426.837 us; speedup vs baseline: 3.7295x; 3.7295x over previous
//
#include <hip/hip_runtime.h>
#include <hip/hip_bf16.h>
#include <cstdio>
#include <cstdint>

#define BATCH 8
#define CIN 256
#define L0 16384
#define NRES 32
#define NSKIP 512
#define NL 50
#define FINAL_LEN 11269
#define NTROW 11392  // 89 * 128 column-tile rows

typedef __attribute__((ext_vector_type(4))) float f32x4v;
typedef __attribute__((ext_vector_type(8))) short s16x8;
typedef __attribute__((ext_vector_type(4))) short s16x4;

// 16B-chunk swizzle within 64B rows: involution, gives 2-way-max bank aliasing
__device__ __forceinline__ int SWS(int r, int s) {
    return s ^ (r & 3) ^ ((r >> 2) & 1);
}
__device__ __forceinline__ short f2bf(float f) {
    __hip_bfloat16 h = __float2bfloat16(f);
    return *reinterpret_cast<short*>(&h);
}
__device__ __forceinline__ void gload16(const void* g, void* l) {
    __builtin_amdgcn_global_load_lds(
        (const __attribute__((address_space(1))) unsigned int*)g,
        (__attribute__((address_space(3))) unsigned int*)l, 16, 0, 0);
}

// ---------------------------------------------------------------- bias sum
__global__ void k_bias_sum(const float* __restrict__ b_skip, float* __restrict__ bsum) {
    int o = threadIdx.x;
    if (o < NSKIP) {
        float s = 0.f;
        for (int i = 0; i < NL; ++i) s += b_skip[i * NSKIP + o];
        bsum[o] = s;
    }
}

// ---------------------------------------------------------------- weight converts (fp32 -> bf16, pre-swizzled)
__global__ __launch_bounds__(256) void k_cvt_skip(const float* __restrict__ w, short* __restrict__ out) {
    int idx = blockIdx.x * 256 + threadIdx.x;
    if (idx >= NSKIP * NL) return;
    int o = idx % NSKIP, ly = idx / NSKIP;
    const float* src = w + ((size_t)ly * NSKIP + o) * NRES;
    size_t base = (size_t)o * (NL * NRES) + ly * NRES;
#pragma unroll
    for (int s = 0; s < 4; ++s) {
        s16x8 v;
#pragma unroll
        for (int j = 0; j < 8; ++j) v[j] = f2bf(src[s * 8 + j]);
        *reinterpret_cast<s16x8*>(out + base + SWS(o & 7, s) * 8) = v;
    }
}

__global__ __launch_bounds__(256) void k_cvt_mat(const float* __restrict__ w, short* __restrict__ out, int M) {
    int idx = blockIdx.x * 256 + threadIdx.x;
    if (idx >= M * 16) return;
    int m = idx >> 4, kc = idx & 15;
    const float* src = w + (size_t)m * 512 + kc * 32;
    size_t base = (size_t)m * 512 + kc * 32;
#pragma unroll
    for (int s = 0; s < 4; ++s) {
        s16x8 v;
#pragma unroll
        for (int j = 0; j < 8; ++j) v[j] = f2bf(src[s * 8 + j]);
        *reinterpret_cast<s16x8*>(out + base + SWS(m & 7, s) * 8) = v;
    }
}

// combined gated-conv weights: Wc[i][64 out][64 k], k = tap*32 + c ; Wres[i][32][32]
__global__ __launch_bounds__(256) void k_cvt_w(
    const float* __restrict__ ws, const float* __restrict__ wt, const float* __restrict__ wr,
    short* __restrict__ Wc, short* __restrict__ Wres) {
    int idx = blockIdx.x * 256 + threadIdx.x;
    if (idx < NL * 64 * 64) {
        int k = idx & 63, o = (idx >> 6) & 63, i = idx >> 12;
        int c = k & 31, tap = k >> 5;
        float v = (o < 32) ? ws[((i * NRES + o) * NRES + c) * 2 + tap]
                           : wt[((i * NRES + (o - 32)) * NRES + c) * 2 + tap];
        Wc[idx] = f2bf(v);
    } else {
        int j = idx - NL * 64 * 64;
        if (j < NL * 32 * 32) Wres[j] = f2bf(wr[j]);
    }
}

// ---------------------------------------------------------------- zero gatesT tail rows
__global__ __launch_bounds__(256) void k_zero_tail(short* __restrict__ gT) {
    int i = blockIdx.x * 256 + threadIdx.x;
    const int per_b = (NTROW - FINAL_LEN) * 200;
    if (i >= BATCH * per_b) return;
    int b = i / per_b, r = i % per_b;
    int row = FINAL_LEN + r / 200, c = r % 200;
    s16x8 z = {0, 0, 0, 0, 0, 0, 0, 0};
    *reinterpret_cast<s16x8*>(gT + ((size_t)b * NTROW + row) * (NL * NRES) + c * 8) = z;
}

// ---------------------------------------------------------------- input 1x1 conv 256->32, t-major fp32 out
__global__ __launch_bounds__(256) void k_conv_in(
    const float* __restrict__ x, const float* __restrict__ w,
    const float* __restrict__ bias, float* __restrict__ outT) {
    const int b = blockIdx.y;
    const int t = blockIdx.x * 256 + threadIdx.x;
    float acc[NRES];
#pragma unroll
    for (int o = 0; o < NRES; ++o) acc[o] = bias[o];
    const float* xp = x + (size_t)b * CIN * L0 + t;
    for (int c = 0; c < CIN; ++c) {
        float xv = xp[(size_t)c * L0];
#pragma unroll
        for (int o = 0; o < NRES; ++o) acc[o] = fmaf(w[o * CIN + c], xv, acc[o]);
    }
    float* op = outT + ((size_t)b * L0 + t) * NRES;
#pragma unroll
    for (int s = 0; s < 8; ++s) {
        f32x4v v = {acc[s * 4], acc[s * 4 + 1], acc[s * 4 + 2], acc[s * 4 + 3]};
        *reinterpret_cast<f32x4v*>(op + s * 4) = v;
    }
}

// ---------------------------------------------------------------- one WaveNet layer (t-major, MFMA)
// residual stream fp32 t-major [b][t][32]; gates to gatesT (bf16, producer-swizzled)
__global__ __launch_bounds__(256) void k_layer_t(
    const float* __restrict__ srcF, float* __restrict__ dstF,
    short* __restrict__ gout,          // gatesT + layer*32
    const short* __restrict__ Wc,      // [64][64] this layer
    const short* __restrict__ Wr,      // [32][32] this layer
    const float* __restrict__ bsig, const float* __restrict__ btan,
    const float* __restrict__ bres, int d, int out_len) {
    const int tid = threadIdx.x;
    const int l = tid & 63, wv = tid >> 6;
    const int lr = l & 15, lg = l >> 4;
    const int b = blockIdx.y;
    const int t0w = blockIdx.x * 256 + wv * 64;
    const int t0g = out_len - FINAL_LEN;

    __shared__ short gsm[4][64][40];  // per-wave gate slices (pad 40: <=2-way banks)

    // op0 fragments (verified convention: M[l&15][(l>>4)*8+i])
    s16x8 aW[4][2], aR[2];
#pragma unroll
    for (int mf = 0; mf < 4; ++mf)
#pragma unroll
        for (int kf = 0; kf < 2; ++kf)
            aW[mf][kf] = *reinterpret_cast<const s16x8*>(&Wc[(mf * 16 + lr) * 64 + kf * 32 + lg * 8]);
#pragma unroll
    for (int mf = 0; mf < 2; ++mf)
        aR[mf] = *reinterpret_cast<const s16x8*>(&Wr[(mf * 16 + lr) * 32 + lg * 8]);

    float bs2[2][4], bt2[2][4], br2[2][4];
#pragma unroll
    for (int mf = 0; mf < 2; ++mf)
#pragma unroll
        for (int j = 0; j < 4; ++j) {
            int o = mf * 16 + lg * 4 + j;
            bs2[mf][j] = bsig[o]; bt2[mf][j] = btan[o]; br2[mf][j] = bres[o];
        }

    const float* sFb = srcF + (size_t)b * L0 * NRES;
    float* dFb = dstF + (size_t)b * L0 * NRES;
    short* go = gout + (size_t)b * NTROW * (NL * NRES);

#pragma unroll 1
    for (int nf = 0; nf < 4; ++nf) {
        const int tl = nf * 16 + lr;
        const int t = t0w + tl;
        const int tc = t < out_len ? t : (out_len - 1);
        // B-fragments: fp32 t-major rows -> bf16 in-register
        f32x4v x0a = *reinterpret_cast<const f32x4v*>(&sFb[(size_t)tc * NRES + lg * 8]);
        f32x4v x0b = *reinterpret_cast<const f32x4v*>(&sFb[(size_t)tc * NRES + lg * 8 + 4]);
        f32x4v x1a = *reinterpret_cast<const f32x4v*>(&sFb[(size_t)(tc + d) * NRES + lg * 8]);
        f32x4v x1b = *reinterpret_cast<const f32x4v*>(&sFb[(size_t)(tc + d) * NRES + lg * 8 + 4]);
        s16x8 bx0, bx1;
#pragma unroll
        for (int j = 0; j < 4; ++j) {
            bx0[j] = f2bf(x0a[j]); bx0[4 + j] = f2bf(x0b[j]);
            bx1[j] = f2bf(x1a[j]); bx1[4 + j] = f2bf(x1b[j]);
        }

        f32x4v acc[4];
#pragma unroll
        for (int mf = 0; mf < 4; ++mf) acc[mf] = {0.f, 0.f, 0.f, 0.f};
#pragma unroll
        for (int mf = 0; mf < 4; ++mf) {
            acc[mf] = __builtin_amdgcn_mfma_f32_16x16x32_bf16(aW[mf][0], bx0, acc[mf], 0, 0, 0);
            acc[mf] = __builtin_amdgcn_mfma_f32_16x16x32_bf16(aW[mf][1], bx1, acc[mf], 0, 0, 0);
        }

        // gate nonlinearity: sig frag mf, tanh frag mf+2 — same lane, same slot
#pragma unroll
        for (int mf = 0; mf < 2; ++mf) {
            s16x4 gq;
#pragma unroll
            for (int j = 0; j < 4; ++j) {
                float Ps = acc[mf][j] + bs2[mf][j];
                float Pt = acc[mf + 2][j] + bt2[mf][j];
                float sg = 1.f / (1.f + __expf(-Ps));
                float e2 = __expf(2.f * Pt);
                float th = 1.f - 2.f / (e2 + 1.f);
                gq[j] = f2bf(sg * th);
            }
            *reinterpret_cast<s16x4*>(&gsm[wv][tl][mf * 16 + lg * 4]) = gq;
        }
        // per-wave LDS producer->consumer handoff (cross-lane within wave only)
        asm volatile("s_waitcnt lgkmcnt(0)" ::: "memory");
        __builtin_amdgcn_sched_barrier(0);  // rule #18: don't let MFMA hoist past the wait

        s16x8 bg = *reinterpret_cast<const s16x8*>(&gsm[wv][tl][lg * 8]);
        f32x4v accR[2];
#pragma unroll
        for (int mf = 0; mf < 2; ++mf) {
            accR[mf] = {0.f, 0.f, 0.f, 0.f};
            accR[mf] = __builtin_amdgcn_mfma_f32_16x16x32_bf16(aR[mf], bg, accR[mf], 0, 0, 0);
        }

        if (t < out_len) {
#pragma unroll
            for (int mf = 0; mf < 2; ++mf) {
                f32x4v rv = *reinterpret_cast<const f32x4v*>(&sFb[(size_t)(t + d) * NRES + mf * 16 + lg * 4]);
                f32x4v ov;
#pragma unroll
                for (int j = 0; j < 4; ++j) ov[j] = accR[mf][j] + br2[mf][j] + rv[j];
                *reinterpret_cast<f32x4v*>(&dFb[(size_t)t * NRES + mf * 16 + lg * 4]) = ov;
            }
        }
    }
    asm volatile("s_waitcnt lgkmcnt(0)" ::: "memory");
    __builtin_amdgcn_sched_barrier(0);

    // coalesced gate repack: full 64B-line stores (SWS permutes 16B chunks in-line)
#pragma unroll
    for (int k = 0; k < 4; ++k) {
        int r = k * 16 + (l >> 2);
        int t = t0w + r;
        int c = l & 3;
        if (t >= t0g && t < out_len) {
            int tg = t - t0g;
            s16x8 gv = *reinterpret_cast<const s16x8*>(&gsm[wv][r][c * 8]);
            *reinterpret_cast<s16x8*>(&go[(size_t)tg * (NL * NRES) + SWS(tg & 7, c) * 8]) = gv;
        }
    }
}

// ---------------------------------------------------------------- MFMA GEMM (XCD-locality 1D grid decode)
// blocks with same t-panel land on same XCD (ids congruent mod 8) -> B panel L2 reuse across m-tiles
template <int KTOT, bool DOELU, int OUTMODE, int NM>
__global__ __launch_bounds__(256) void k_mm(
    const short* __restrict__ A, const float* __restrict__ bias,
    const short* __restrict__ B, short* __restrict__ outS,
    float* __restrict__ outF, int Mtot) {
    const int tid = threadIdx.x;
    const int l = tid & 63, w = tid >> 6;

    const int id = blockIdx.x;
    const int rr = id % (8 * NM);
    const int ttile = (id / (8 * NM)) * 8 + (rr & 7);
    if (ttile >= NTROW / 128) return;
    const int t0 = ttile * 128;
    const int m0 = (rr >> 3) * 128;
    const int bb = blockIdx.z;

    __shared__ __attribute__((aligned(16))) char Asm_[2][8192];
    __shared__ __attribute__((aligned(16))) char Bsm_[2][8192];

    const char* Ag = (const char*)A;
    const char* Bg = (const char*)B + (size_t)bb * NTROW * (KTOT * 2);

    const int rstage = w * 16 + (l >> 2);
    const char* a0 = Ag + (size_t)(m0 + rstage) * (KTOT * 2) + (l & 3) * 16;
    const char* a1 = a0 + (size_t)64 * (KTOT * 2);
    const char* b0 = Bg + (size_t)(t0 + rstage) * (KTOT * 2) + (l & 3) * 16;
    const char* b1 = b0 + (size_t)64 * (KTOT * 2);

    const int wm = (w >> 1) * 64, wn = (w & 1) * 64;
    const int slotSw = ((l >> 4) ^ (l & 3) ^ ((l >> 2) & 1)) * 16;
    const int aoff = (wm + (l & 15)) * 64 + slotSw;
    const int boff = (wn + (l & 15)) * 64 + slotSw;

    f32x4v acc[4][4];
#pragma unroll
    for (int i = 0; i < 4; ++i)
#pragma unroll
        for (int j = 0; j < 4; ++j) acc[i][j] = {0.f, 0.f, 0.f, 0.f};

    constexpr int NKT = KTOT / 32;
    gload16(a0, &Asm_[0][w * 1024]);
    gload16(a1, &Asm_[0][4096 + w * 1024]);
    gload16(b0, &Bsm_[0][w * 1024]);
    gload16(b1, &Bsm_[0][4096 + w * 1024]);
    __syncthreads();

    for (int kt = 0; kt < NKT; ++kt) {
        const int cur = kt & 1;
        if (kt + 1 < NKT) {
            size_t ko = (size_t)(kt + 1) * 64;
            gload16(a0 + ko, &Asm_[cur ^ 1][w * 1024]);
            gload16(a1 + ko, &Asm_[cur ^ 1][4096 + w * 1024]);
            gload16(b0 + ko, &Bsm_[cur ^ 1][w * 1024]);
            gload16(b1 + ko, &Bsm_[cur ^ 1][4096 + w * 1024]);
        }
        s16x8 af[4], bf_[4];
#pragma unroll
        for (int i = 0; i < 4; ++i)
            af[i] = *reinterpret_cast<const s16x8*>(&Asm_[cur][aoff + i * 1024]);
#pragma unroll
        for (int i = 0; i < 4; ++i)
            bf_[i] = *reinterpret_cast<const s16x8*>(&Bsm_[cur][boff + i * 1024]);
#pragma unroll
        for (int i = 0; i < 4; ++i)
#pragma unroll
            for (int j = 0; j < 4; ++j)
                acc[i][j] = __builtin_amdgcn_mfma_f32_16x16x32_bf16(af[i], bf_[j], acc[i][j], 0, 0, 0);
        __syncthreads();
    }

    const int colc = l & 15;
    const int rowc = (l >> 4) * 4;
#pragma unroll
    for (int mf = 0; mf < 4; ++mf) {
        const int ch = m0 + wm + mf * 16 + rowc;
        const float4 bv = *reinterpret_cast<const float4*>(&bias[ch]);
        const float* bvp = (const float*)&bv;
#pragma unroll
        for (int nf = 0; nf < 4; ++nf) {
            const int t = t0 + wn + nf * 16 + colc;
            float vb[4];
#pragma unroll
            for (int j = 0; j < 4; ++j) {
                float v = acc[mf][nf][j] + bvp[j];
                if (DOELU) v = v > 0.f ? v : (__expf(v) - 1.f);
                vb[j] = v;
            }
            if (OUTMODE == 0) {
                s16x4 pv;
#pragma unroll
                for (int j = 0; j < 4; ++j) pv[j] = f2bf(vb[j]);
                size_t el = ((size_t)bb * NTROW + t) * 512 + (ch >> 5) * 32
                          + SWS(t & 7, (ch >> 3) & 3) * 8 + (ch & 7);
                *reinterpret_cast<s16x4*>(outS + el) = pv;
            } else {
                if (t < FINAL_LEN) {
#pragma unroll
                    for (int j = 0; j < 4; ++j)
                        outF[((size_t)bb * Mtot + ch + j) * FINAL_LEN + t] = vb[j];
                }
            }
        }
    }
}

// ---------------------------------------------------------------- host
extern "C" void kernel_launch(void* const* d_in, const int* in_sizes, int n_in,
                              void* d_out, int out_size, void* d_ws, size_t ws_size,
                              hipStream_t stream) {
    const float* x      = (const float*)d_in[0];
    const float* w_in   = (const float*)d_in[1];
    const float* b_in   = (const float*)d_in[2];
    const float* w_sig  = (const float*)d_in[3];
    const float* b_sig  = (const float*)d_in[4];
    const float* w_tanh = (const float*)d_in[5];
    const float* b_tanh = (const float*)d_in[6];
    const float* w_skip = (const float*)d_in[7];
    const float* b_skip = (const float*)d_in[8];
    const float* w_res  = (const float*)d_in[9];
    const float* b_res  = (const float*)d_in[10];
    const float* w_p1   = (const float*)d_in[11];
    const float* b_p1   = (const float*)d_in[12];
    const float* w_p2   = (const float*)d_in[13];
    const float* b_p2   = (const float*)d_in[14];
    float* out = (float*)d_out;

    float* bufA   = (float*)d_ws;
    float* bufB   = bufA + (size_t)BATCH * NRES * L0;
    float* bsum   = bufB + (size_t)BATCH * NRES * L0;
    short* Askip  = (short*)(bsum + NSKIP);
    short* Ap1    = Askip + (size_t)NSKIP * NL * NRES;
    short* Ap2    = Ap1 + (size_t)NSKIP * NSKIP;
    short* WcH    = Ap2 + (size_t)CIN * NSKIP;
    short* WresH  = WcH + (size_t)NL * 64 * 64;
    short* gatesT = WresH + (size_t)NL * 32 * 32;
    short* hbufT  = gatesT + (size_t)BATCH * NTROW * (NL * NRES);
    short* h2bufT = gatesT;  // alias: gatesT dead after skip GEMM

    size_t need = (size_t)((char*)(hbufT + (size_t)BATCH * NTROW * NSKIP) - (char*)d_ws);
    if (ws_size < need)
        fprintf(stderr, "WS TOO SMALL: have %zu need %zu\n", ws_size, need);

    k_bias_sum<<<1, 512, 0, stream>>>(b_skip, bsum);
    k_cvt_skip<<<(NSKIP * NL + 255) / 256, 256, 0, stream>>>(w_skip, Askip);
    k_cvt_mat<<<(NSKIP * 16 + 255) / 256, 256, 0, stream>>>(w_p1, Ap1, NSKIP);
    k_cvt_mat<<<(CIN * 16 + 255) / 256, 256, 0, stream>>>(w_p2, Ap2, CIN);
    k_cvt_w<<<(NL * 64 * 64 + NL * 32 * 32 + 255) / 256, 256, 0, stream>>>(
        w_sig, w_tanh, w_res, WcH, WresH);
    k_zero_tail<<<(BATCH * (NTROW - FINAL_LEN) * 200 + 255) / 256, 256, 0, stream>>>(gatesT);
    k_conv_in<<<dim3(L0 / 256, BATCH), 256, 0, stream>>>(x, w_in, b_in, bufA);

    float* srcF = bufA;
    float* dstF = bufB;
    int len = L0;
    for (int i = 0; i < NL; ++i) {
        int d = 1 << (i % 10);
        int out_len = len - d;
        dim3 grid((out_len + 255) / 256, BATCH);
        k_layer_t<<<grid, 256, 0, stream>>>(
            srcF, dstF, gatesT + (size_t)i * NRES,
            WcH + (size_t)i * 4096, WresH + (size_t)i * 1024,
            b_sig + i * 32, b_tanh + i * 32, b_res + i * 32, d, out_len);
        float* tf = srcF; srcF = dstF; dstF = tf;
        len = out_len;
    }

    k_mm<1600, true, 0, 4><<<dim3(384, 1, BATCH), 256, 0, stream>>>(Askip, bsum, gatesT, hbufT, nullptr, NSKIP);
    k_mm<512,  true, 0, 4><<<dim3(384, 1, BATCH), 256, 0, stream>>>(Ap1, b_p1, hbufT, h2bufT, nullptr, NSKIP);
    k_mm<512, false, 1, 2><<<dim3(192, 1, BATCH), 256, 0, stream>>>(Ap2, b_p2, h2bufT, nullptr, out, CIN);
}